// Round 13
// baseline (7797.962 us; speedup 1.0000x reference)
//
#include <hip/hip_runtime.h>
#include <math.h>

#define B_ 32
#define T_ 1024
#define M_ 40

// ---------------- weight prep ----------------
// Wst: rnn streaming layout. idx = ((s*64+ks*16+g)*192+jq)*8 + r2*4+kk
//   row=2jq+r2 (0..383), gate=row>>7, jloc=row&127, j_glob=gate*256+s*128+jloc,
//   k=ks*64+g*4+kk.
__global__ void prep_kernel(const float* __restrict__ W_hh, const float* __restrict__ W2,
                            const float* __restrict__ W3, const float* __restrict__ W_ih,
                            float* __restrict__ Wst, float* __restrict__ W2t,
                            float* __restrict__ W3t, float* __restrict__ WihT4) {
  int idx = blockIdx.x * 256 + threadIdx.x;
  if (idx < 196608) {
    int s = idx / 98304, rem = idx % 98304;
    int ks = rem / 24576, g = (rem / 1536) % 16, jq = (rem / 8) % 192;
    int r2 = (rem / 4) % 2, kk = rem % 4;
    int row = 2 * jq + r2;
    int jg = (row >> 7) * 256 + s * 128 + (row & 127);
    int k = ks * 64 + g * 4 + kk;
    Wst[idx] = W_hh[jg * 256 + k];
    return;
  }
  idx -= 196608;
  if (idx < 147456) {  // W2t[tap][ci][co]
    int tap = idx >> 14, ci = (idx >> 7) & 127, co = idx & 127;
    W2t[idx] = W2[(co * 128 + ci) * 9 + tap];
    return;
  }
  idx -= 147456;
  if (idx < 147456) {  // W3t[tap][ci][co]
    int tap = idx >> 14, ci = (idx >> 7) & 127, co = idx & 127;
    W3t[idx] = W3[(co * 128 + ci) * 9 + tap];
    return;
  }
  idx -= 147456;
  if (idx < 98304) {  // WihT4[k/4][j][k%4] = W_ih[j][k] (x-part, k<128)
    int khi = idx / 3072, rem = idx % 3072, j = rem >> 2, klo = rem & 3;
    WihT4[idx] = W_ih[j * 138 + khi * 4 + klo];
  }
}

// ---------------- fused conv1+pool5 + conv2+pool4 ----------------
// grid (T/4, B), block 256.  y2: [B][T][2][128]
__global__ __launch_bounds__(256) void conv12_kernel(
    const float* __restrict__ x, const float* __restrict__ W1, const float* __restrict__ b1,
    const float* __restrict__ W2t, const float* __restrict__ b2, float* __restrict__ y2) {
  __shared__ float xt[8 * 42];          // x rows t0-2..t0+5, mel slots -1..40
  __shared__ float y1s[6 * 128 * 12];   // y1 rows t0-1..t0+4, [row][c][mslot 0..9 (=-1..8), pad]
  const int tid = threadIdx.x;
  const int t0 = blockIdx.x * 4;
  const int b = blockIdx.y;
  for (int idx = tid; idx < 8 * 42; idx += 256) {
    int row = idx / 42, slot = idx % 42;
    int t_in = t0 - 2 + row, m = slot - 1;
    float v = 0.f;
    if (t_in >= 0 && t_in < T_ && m >= 0 && m < M_) v = x[(b * T_ + t_in) * M_ + m];
    xt[idx] = v;
  }
  __syncthreads();
  const int c = tid & 127, q = tid >> 7;
  float w1[9];
#pragma unroll
  for (int i = 0; i < 9; ++i) w1[i] = W1[c * 9 + i];
  const float b1c = b1[c];
  for (int rr = 0; rr < 3; ++rr) {
    const int r = q * 3 + rr;
    const int t_in = t0 - 1 + r;
    float* yrow = &y1s[(r * 128 + c) * 12];
    if (t_in < 0 || t_in >= T_) {
#pragma unroll
      for (int s = 0; s < 12; ++s) yrow[s] = 0.f;
    } else {
      yrow[0] = 0.f; yrow[9] = 0.f; yrow[10] = 0.f; yrow[11] = 0.f;
#pragma unroll
      for (int mo = 0; mo < 8; ++mo) {
        float mx = -1e30f;
#pragma unroll
        for (int i5 = 0; i5 < 5; ++i5) {
          const int mp = mo * 5 + i5;
          float s = b1c;
#pragma unroll
          for (int dt = 0; dt < 3; ++dt)
#pragma unroll
            for (int dm = 0; dm < 3; ++dm)
              s += xt[(r + dt) * 42 + mp + dm] * w1[dt * 3 + dm];
          mx = fmaxf(mx, s);
        }
        yrow[1 + mo] = fmaxf(mx, 0.f);  // relu after (pool of conv+b); relu monotone
      }
    }
  }
  __syncthreads();
  // conv2: thread (co, tq) computes 2 t x 8 m outputs
  const int co = c, tq = q;
  float acc[2][8];
#pragma unroll
  for (int tl = 0; tl < 2; ++tl)
#pragma unroll
    for (int mo = 0; mo < 8; ++mo) acc[tl][mo] = 0.f;
  for (int ci = 0; ci < 128; ++ci) {
    float w[9];
#pragma unroll
    for (int i = 0; i < 9; ++i) w[i] = W2t[i * 16384 + ci * 128 + co];
    float xv[4][10];
#pragma unroll
    for (int rr = 0; rr < 4; ++rr) {
      const float* p = &y1s[((2 * tq + rr) * 128 + ci) * 12];
      const float4 a = *(const float4*)p;
      const float4 bq = *(const float4*)(p + 4);
      const float2 cq = *(const float2*)(p + 8);
      xv[rr][0] = a.x; xv[rr][1] = a.y; xv[rr][2] = a.z; xv[rr][3] = a.w;
      xv[rr][4] = bq.x; xv[rr][5] = bq.y; xv[rr][6] = bq.z; xv[rr][7] = bq.w;
      xv[rr][8] = cq.x; xv[rr][9] = cq.y;
    }
#pragma unroll
    for (int dt = 0; dt < 3; ++dt)
#pragma unroll
      for (int dm = 0; dm < 3; ++dm) {
        const float wv = w[dt * 3 + dm];
#pragma unroll
        for (int tl = 0; tl < 2; ++tl)
#pragma unroll
          for (int mo = 0; mo < 8; ++mo)
            acc[tl][mo] += xv[tl + dt][mo + dm] * wv;
      }
  }
  const float b2c = b2[co];
#pragma unroll
  for (int tl = 0; tl < 2; ++tl) {
    const int t = t0 + 2 * tq + tl;
    float m0 = fmaxf(fmaxf(acc[tl][0], acc[tl][1]), fmaxf(acc[tl][2], acc[tl][3])) + b2c;
    float m1 = fmaxf(fmaxf(acc[tl][4], acc[tl][5]), fmaxf(acc[tl][6], acc[tl][7])) + b2c;
    y2[((b * T_ + t) * 2 + 0) * 128 + co] = fmaxf(m0, 0.f);
    y2[((b * T_ + t) * 2 + 1) * 128 + co] = fmaxf(m1, 0.f);
  }
}

// ---------------- conv3+pool2 -> feats [T][B][128] ----------------
__global__ __launch_bounds__(256) void conv3_kernel(
    const float* __restrict__ y2, const float* __restrict__ W3t, const float* __restrict__ b3,
    float* __restrict__ feats) {
  __shared__ float y2s[6 * 128 * 4];  // [row][ci][mslot 0..3 (=-1..2)]
  const int tid = threadIdx.x;
  const int t0 = blockIdx.x * 4;
  const int b = blockIdx.y;
  for (int idx = tid; idx < 768; idx += 256) {
    int row = idx / 128, ci = idx % 128;
    y2s[(row * 128 + ci) * 4 + 0] = 0.f;
    y2s[(row * 128 + ci) * 4 + 3] = 0.f;
  }
  for (int idx = tid; idx < 6 * 256; idx += 256) {
    int row = idx / 256, rem = idx % 256;
    int m = rem >> 7, ci = rem & 127;
    int t_in = t0 - 1 + row;
    float v = 0.f;
    if (t_in >= 0 && t_in < T_) v = y2[((b * T_ + t_in) * 2 + m) * 128 + ci];
    y2s[(row * 128 + ci) * 4 + 1 + m] = v;
  }
  __syncthreads();
  const int co = tid & 127, tq = tid >> 7;
  float acc[2][2] = {{0.f, 0.f}, {0.f, 0.f}};
  for (int ci = 0; ci < 128; ++ci) {
    float w[9];
#pragma unroll
    for (int i = 0; i < 9; ++i) w[i] = W3t[i * 16384 + ci * 128 + co];
    float4 xr[4];
#pragma unroll
    for (int rr = 0; rr < 4; ++rr)
      xr[rr] = *(const float4*)&y2s[((2 * tq + rr) * 128 + ci) * 4];
#pragma unroll
    for (int dt = 0; dt < 3; ++dt)
#pragma unroll
      for (int tl = 0; tl < 2; ++tl) {
        const float4 v = xr[tl + dt];
        acc[tl][0] += v.y * w[dt * 3 + 1] + v.z * w[dt * 3 + 2];  // m=0: taps dm=1,2
        acc[tl][1] += v.y * w[dt * 3 + 0] + v.z * w[dt * 3 + 1];  // m=1: taps dm=0,1
      }
  }
  const float b3c = b3[co];
#pragma unroll
  for (int tl = 0; tl < 2; ++tl) {
    const int t = t0 + 2 * tq + tl;
    float f = fmaxf(fmaxf(acc[tl][0], acc[tl][1]) + b3c, 0.f);
    feats[(t * B_ + b) * 128 + co] = f;
  }
}

// ---------------- gi_x = feats @ W_ih_x^T + b_ih -> [T*B][768] ----------------
__global__ __launch_bounds__(256) void gid_kernel(
    const float* __restrict__ feats, const float* __restrict__ WihT4,
    const float* __restrict__ b_ih, float* __restrict__ gi) {
  __shared__ float fs[32 * 128];
  const int tid = threadIdx.x;
  const int jb = blockIdx.x;  // 0..2
  const int rb = blockIdx.y;  // 0..1023
  const float4* src = (const float4*)(feats + rb * 32 * 128);
  float4* dst = (float4*)fs;
  for (int i = tid; i < 1024; i += 256) dst[i] = src[i];
  __syncthreads();
  const int j = jb * 256 + tid;
  float acc[32];
#pragma unroll
  for (int r = 0; r < 32; ++r) acc[r] = 0.f;
  for (int k4 = 0; k4 < 32; ++k4) {
    const float4 w4 = *(const float4*)&WihT4[(k4 * 768 + j) * 4];
#pragma unroll
    for (int r = 0; r < 32; ++r) {
      const float4 f4 = *(const float4*)&fs[r * 128 + k4 * 4];
      acc[r] += f4.x * w4.x + f4.y * w4.y + f4.z * w4.z + f4.w * w4.w;
    }
  }
  const float bj = b_ih[j];
  for (int r = 0; r < 32; ++r) gi[(rb * 32 + r) * 768 + j] = acc[r] + bj;
}

// ---------------- paired GRU: 64 blocks = 32 batches x 2 j-halves ----------------
// Block (b, s) owns 384 gate-rows (gate*256 + s*128 + jloc). LDS caches 5 of 16
// k-groups (120 KB); streams 264 KB/step (vs R9's 672). Per step the pair
// exchanges 128 h floats via L2 with a monotone release/acquire flag (R4-style,
// but 1 partner not 7). Pair (i, i+32): same XCD under round-robin (speed-only
// heuristic; correctness independent). FMA order bit-identical to R9.
__global__ __launch_bounds__(768) void rnn_kernel(
    const float* __restrict__ gi, const float* __restrict__ Wst,
    const float* __restrict__ W_ih, const float* __restrict__ b_hh,
    const float* __restrict__ Wf, const float* __restrict__ bf,
    const float* __restrict__ targets, const int* __restrict__ force_mask,
    float* __restrict__ out, float* __restrict__ hx, unsigned* __restrict__ flags) {
  __shared__ float Wg[20 * 1536];   // 5 groups x 4 fp x 1536   = 120 KB
  __shared__ float h_s[256];
  __shared__ float part[4 * 384];   // 6 KB
  __shared__ float gis[384];
  __shared__ float wtf[10 * 384];   // 15 KB  [cc][row]
  __shared__ float wfs[10 * 256];   // 10 KB
  __shared__ float bhh_s[384];
  __shared__ float tf_s[16];
  __shared__ float bf_s[16];
  const int tid = threadIdx.x;
  const int b = blockIdx.x & 31;
  const int s = blockIdx.x >> 5;    // 0 or 1 (pair i, i+32 -> same XCD heuristic)
  for (int idx = tid; idx < 3840; idx += 768) {
    int cc = idx / 384, row = idx % 384;
    int jg = (row >> 7) * 256 + s * 128 + (row & 127);
    wtf[idx] = W_ih[jg * 138 + 128 + cc];
  }
  for (int idx = tid; idx < 2560; idx += 768) wfs[idx] = Wf[idx];
  if (tid < 384) {
    int jg = (tid >> 7) * 256 + s * 128 + (tid & 127);
    bhh_s[tid] = b_hh[jg];
  }
  if (tid < 256) h_s[tid] = 0.f;
  if (tid < 10) { tf_s[tid] = 0.f; bf_s[tid] = bf[tid]; }
  const int ks = tid / 192;   // k-slice (wave-uniform)
  const int jq = tid % 192;   // row-pair: rows 2jq, 2jq+1
  const float* wbase = Wst + (s * 64 + ks * 16) * 1536 + jq * 8;
  // LDS-cache k-groups 0..4 (pair-interleaved: fp slots stride 1536, tid*2 -> 2-way=free)
#pragma unroll
  for (int g = 0; g < 5; ++g) {
    const float4 v0 = *(const float4*)(wbase + g * 1536);      // row 2jq,  k 0..3
    const float4 v1 = *(const float4*)(wbase + g * 1536 + 4);  // row 2jq+1, k 0..3
    Wg[(g * 4 + 0) * 1536 + tid * 2 + 0] = v0.x; Wg[(g * 4 + 0) * 1536 + tid * 2 + 1] = v0.y;
    Wg[(g * 4 + 1) * 1536 + tid * 2 + 0] = v0.z; Wg[(g * 4 + 1) * 1536 + tid * 2 + 1] = v0.w;
    Wg[(g * 4 + 2) * 1536 + tid * 2 + 0] = v1.x; Wg[(g * 4 + 2) * 1536 + tid * 2 + 1] = v1.y;
    Wg[(g * 4 + 3) * 1536 + tid * 2 + 0] = v1.z; Wg[(g * 4 + 3) * 1536 + tid * 2 + 1] = v1.w;
  }
  __syncthreads();

  auto matvec = [&](int tt) {
    float giv = 0.f;
    if (tid < 384)
      giv = gi[(tt * B_ + b) * 768 + (tid >> 7) * 256 + s * 128 + (tid & 127)];
    float ax = 0.f, ay = 0.f;  // rows 2jq, 2jq+1
    // k-groups 0..4 from LDS (ascending; inner order k0..k3 — same as R9)
#pragma unroll
    for (int g = 0; g < 5; ++g) {
      const float4 h4 = *(const float4*)&h_s[ks * 64 + g * 4];
      const float* bw = &Wg[(g * 4) * 1536 + tid * 2];
      const float2 p0 = *(const float2*)(bw);
      const float2 p1 = *(const float2*)(bw + 1536);
      const float2 p2 = *(const float2*)(bw + 3072);
      const float2 p3 = *(const float2*)(bw + 4608);
      ax += p0.x * h4.x + p0.y * h4.y + p1.x * h4.z + p1.y * h4.w;
      ay += p2.x * h4.x + p2.y * h4.y + p3.x * h4.z + p3.y * h4.w;
    }
    // k-groups 5..15 streamed from L2 (264 KB/step/block)
    const float* wp = wbase + 5 * 1536;
#pragma unroll 2
    for (int g = 5; g < 16; ++g) {
      const float4 v0 = *(const float4*)(wp);
      const float4 v1 = *(const float4*)(wp + 4);
      const float4 h4 = *(const float4*)&h_s[ks * 64 + g * 4];
      ax += v0.x * h4.x + v0.y * h4.y + v0.z * h4.z + v0.w * h4.w;
      ay += v1.x * h4.x + v1.y * h4.y + v1.z * h4.z + v1.w * h4.w;
      wp += 1536;
    }
    *(float2*)&part[ks * 384 + jq * 2] = make_float2(ax, ay);
    if (tid < 384) gis[tid] = giv;
  };

  int fm_r = 0;
  float tg_r[10];
  if (tid == 0) {
    fm_r = force_mask[0 * B_ + b];
#pragma unroll
    for (int cc = 0; cc < 10; ++cc) tg_r[cc] = targets[(b * T_ + 0) * 10 + cc];
  }
  matvec(0);
  __syncthreads();  // S1

  for (int t = 0; t < T_; ++t) {
    const int p = t & 1;
    // A: gate phase (tid<128 -> jloc)
    if (tid < 128) {
      float gr = gis[tid], gz = gis[128 + tid], gn0 = gis[256 + tid];
#pragma unroll
      for (int cc = 0; cc < 10; ++cc) {
        const float tfv = tf_s[cc];
        gr += wtf[cc * 384 + tid] * tfv;
        gz += wtf[cc * 384 + 128 + tid] * tfv;
        gn0 += wtf[cc * 384 + 256 + tid] * tfv;
      }
      float ghr = bhh_s[tid] + part[tid] + part[384 + tid] + part[768 + tid] + part[1152 + tid];
      float ghz = bhh_s[128 + tid] + part[128 + tid] + part[512 + tid] + part[896 + tid] + part[1280 + tid];
      float ghn = bhh_s[256 + tid] + part[256 + tid] + part[640 + tid] + part[1024 + tid] + part[1408 + tid];
      const float r = 1.f / (1.f + expf(-(gr + ghr)));
      const float z = 1.f / (1.f + expf(-(gz + ghz)));
      const float n = tanhf(gn0 + r * ghn);
      const float hn = (1.f - z) * n + z * h_s[s * 128 + tid];
      h_s[s * 128 + tid] = hn;
      __hip_atomic_store(&hx[(p * B_ + b) * 256 + s * 128 + tid], hn,
                         __ATOMIC_RELAXED, __HIP_MEMORY_SCOPE_AGENT);
    }
    __syncthreads();  // S2: h half stored
    // B: publish + poll partner (monotone flag)
    if (tid == 0) {
      __hip_atomic_store(&flags[(b * 2 + s) * 16], (unsigned)(t + 1),
                         __ATOMIC_RELEASE, __HIP_MEMORY_SCOPE_AGENT);
      while (__hip_atomic_load(&flags[(b * 2 + (1 - s)) * 16],
                               __ATOMIC_ACQUIRE, __HIP_MEMORY_SCOPE_AGENT) < (unsigned)(t + 1))
        __builtin_amdgcn_s_sleep(1);
    }
    __syncthreads();  // S3
    // C: read partner half
    if (tid < 128)
      h_s[(1 - s) * 128 + tid] =
          __hip_atomic_load(&hx[(p * B_ + b) * 256 + (1 - s) * 128 + tid],
                            __ATOMIC_RELAXED, __HIP_MEMORY_SCOPE_AGENT);
    __syncthreads();  // S4: full h(t)
    // D: out(t) on wave 0 (both blocks compute tf identically; s==0 writes out)
    if (tid < 64) {
      const float h0 = h_s[tid], h1 = h_s[tid + 64], h2 = h_s[tid + 128], h3 = h_s[tid + 192];
      float pr[10];
#pragma unroll
      for (int cc = 0; cc < 10; ++cc)
        pr[cc] = wfs[cc * 256 + tid] * h0 + wfs[cc * 256 + tid + 64] * h1 +
                 wfs[cc * 256 + tid + 128] * h2 + wfs[cc * 256 + tid + 192] * h3;
#pragma unroll
      for (int off = 32; off > 0; off >>= 1)
#pragma unroll
        for (int cc = 0; cc < 10; ++cc) pr[cc] += __shfl_xor(pr[cc], off);
      if (tid == 0) {
#pragma unroll
        for (int cc = 0; cc < 10; ++cc) {
          const float o = pr[cc] + bf_s[cc];
          if (s == 0) out[(b * T_ + t) * 10 + cc] = o;
          tf_s[cc] = (fm_r > 0) ? tg_r[cc] : (o > 0.f ? 1.f : 0.f);
        }
        if (t + 1 < T_) {
          fm_r = force_mask[(t + 1) * B_ + b];
#pragma unroll
          for (int cc = 0; cc < 10; ++cc) tg_r[cc] = targets[(b * T_ + t + 1) * 10 + cc];
        }
      }
    }
    if (t + 1 < T_) matvec(t + 1);
    __syncthreads();  // S1'
  }
}

extern "C" void kernel_launch(void* const* d_in, const int* in_sizes, int n_in,
                              void* d_out, int out_size, void* d_ws, size_t ws_size,
                              hipStream_t stream) {
  const float* x = (const float*)d_in[0];
  const float* targets = (const float*)d_in[1];
  const int* fmask = (const int*)d_in[2];
  const float* W1 = (const float*)d_in[3];
  const float* b1 = (const float*)d_in[4];
  const float* W2 = (const float*)d_in[5];
  const float* b2 = (const float*)d_in[6];
  const float* W3 = (const float*)d_in[7];
  const float* b3 = (const float*)d_in[8];
  const float* Wih = (const float*)d_in[9];
  const float* Whh = (const float*)d_in[10];
  const float* bih = (const float*)d_in[11];
  const float* bhh = (const float*)d_in[12];
  const float* Wf = (const float*)d_in[13];
  const float* bf = (const float*)d_in[14];
  float* out = (float*)d_out;
  float* ws = (float*)d_ws;
  // workspace layout (floats), peak ~114.3 MiB. y2 aliases gi (y2 dead before gi).
  unsigned* flags = (unsigned*)ws;        // 1024 u32 (64 flags, 64B apart)
  float* hx = ws + 1024;                  // 16384 (2 parities x 32 b x 256)
  float* Wst = ws + 17408;                // 196608
  float* W2t = ws + 214016;               // 147456
  float* W3t = ws + 361472;               // 147456
  float* WihT4 = ws + 508928;             // 98304
  float* feats = ws + 607232;             // 4194304
  float* gi = ws + 4801536;               // 25165824
  float* y2 = gi;                         // 8388608 (alias)

  prep_kernel<<<2304, 256, 0, stream>>>(Whh, W2, W3, Wih, Wst, W2t, W3t, WihT4);
  hipMemsetAsync(flags, 0, 1024 * sizeof(unsigned), stream);
  conv12_kernel<<<dim3(256, 32), 256, 0, stream>>>(x, W1, b1, W2t, b2, y2);
  conv3_kernel<<<dim3(256, 32), 256, 0, stream>>>(y2, W3t, b3, feats);
  gid_kernel<<<dim3(3, 1024), 256, 0, stream>>>(feats, WihT4, bih, gi);
  rnn_kernel<<<64, 768, 0, stream>>>(gi, Wst, Wih, bhh, Wf, bf, targets, fmask, out, hx, flags);
}